// Round 1
// baseline (12573.173 us; speedup 1.0000x reference)
//
#include <hip/hip_runtime.h>
#include <hip/hip_bf16.h>
#include <math.h>

#define S_LEN   800
#define C_DIM   768
#define NHEAD   12
#define DHEAD   64
#define HID_DIM 3072
#define BATCH   4
#define NTOK    (BATCH * S_LEN)   // 3200
#define DEPTH_N 12

// ---------------------------------------------------------------------------
// Transpose conv_w (O=768, K=768) -> wT (K, O)
// ---------------------------------------------------------------------------
__global__ void transpose_w_kernel(const float* __restrict__ Win, float* __restrict__ Wout) {
    int idx = blockIdx.x * 256 + threadIdx.x;          // 768*768 = 589824
    if (idx >= 768 * 768) return;
    int o = idx / 768, kk = idx % 768;
    Wout[kk * 768 + o] = Win[idx];
}

// ---------------------------------------------------------------------------
// im2col for the dual patch embed.
// x: (4, 6, 320, 320).  A[(b*800+s)*768 + kk], kk = c*256 + i*16 + j.
// s<400: channels 0..2 ; s>=400: channels 3..5.
// ---------------------------------------------------------------------------
__global__ void im2col_kernel(const float* __restrict__ x, float* __restrict__ A) {
    int idx = blockIdx.x * 256 + threadIdx.x;          // 4*800*768 = 2457600
    if (idx >= NTOK * 768) return;
    int kk = idx % 768;
    int s  = (idx / 768) % S_LEN;
    int b  = idx / (768 * S_LEN);
    int c  = kk / 256;
    int i  = (kk / 16) % 16;
    int j  = kk % 16;
    int half = s / 400, ss = s % 400;
    int hg = ss / 20, wg = ss % 20;
    int ch = half * 3 + c;
    A[idx] = x[((size_t)(b * 6 + ch) * 320 + hg * 16 + i) * 320 + wg * 16 + j];
}

// ---------------------------------------------------------------------------
// Generic fp32 GEMM: C[M,N] = A[M,K] @ W[K,N] + bias (+res) (+GELU)
// 64x64 tile, BK=16, 256 threads, 4x4 accumulators per thread.
// M,N,K all multiples of 64/16 for every call in this net (no bounds checks).
// ---------------------------------------------------------------------------
template <bool GELU, bool RES>
__global__ __launch_bounds__(256)
void gemm_kernel(const float* __restrict__ A, const float* __restrict__ W,
                 const float* __restrict__ bias, const float* __restrict__ res,
                 float* __restrict__ Cout, int M, int N, int K) {
    __shared__ float As[16][68];   // [kk][mm], pad 68: float4-aligned rows, ~conflict-free
    __shared__ float Bs[16][68];   // [kk][nn]

    int tid = threadIdx.x;
    int tx = tid % 16, ty = tid / 16;
    int m0 = blockIdx.y * 64, n0 = blockIdx.x * 64;

    float acc[4][4] = {};

    for (int k0 = 0; k0 < K; k0 += 16) {
        // Load A tile: thread -> row = tid>>2 (0..63), 4 k's at (tid&3)*4
        {
            int row = tid >> 2, kc = (tid & 3) * 4;
            const float4 av = *(const float4*)(A + (size_t)(m0 + row) * K + k0 + kc);
            As[kc + 0][row] = av.x;
            As[kc + 1][row] = av.y;
            As[kc + 2][row] = av.z;
            As[kc + 3][row] = av.w;
        }
        // Load B tile: thread -> krow = tid>>4 (0..15), 4 n's at (tid&15)*4
        {
            int krow = tid >> 4, nc = (tid & 15) * 4;
            const float4 bv = *(const float4*)(W + (size_t)(k0 + krow) * N + n0 + nc);
            *(float4*)&Bs[krow][nc] = bv;
        }
        __syncthreads();
#pragma unroll
        for (int kk = 0; kk < 16; ++kk) {
            float4 a4 = *(const float4*)&As[kk][ty * 4];
            float4 b4 = *(const float4*)&Bs[kk][tx * 4];
            float a[4] = {a4.x, a4.y, a4.z, a4.w};
            float b[4] = {b4.x, b4.y, b4.z, b4.w};
#pragma unroll
            for (int i = 0; i < 4; ++i)
#pragma unroll
                for (int j = 0; j < 4; ++j)
                    acc[i][j] += a[i] * b[j];
        }
        __syncthreads();
    }

#pragma unroll
    for (int i = 0; i < 4; ++i) {
        int m = m0 + ty * 4 + i;
#pragma unroll
        for (int j = 0; j < 4; ++j) {
            int n = n0 + tx * 4 + j;
            float v = acc[i][j] + bias[n];
            if (RES) v += res[(size_t)m * N + n];
            if (GELU) v = 0.5f * v * (1.0f + erff(v * 0.70710678118654752f));
            Cout[(size_t)m * N + n] = v;
        }
    }
}

// ---------------------------------------------------------------------------
// LayerNorm: one block (256 thr) per row of 768.
// ---------------------------------------------------------------------------
__global__ __launch_bounds__(256)
void ln_kernel(const float* __restrict__ x, const float* __restrict__ g,
               const float* __restrict__ bta, float* __restrict__ y) {
    int row = blockIdx.x;
    const float* xr = x + (size_t)row * C_DIM;
    float* yr = y + (size_t)row * C_DIM;
    int tid = threadIdx.x;

    float v0 = xr[tid], v1 = xr[tid + 256], v2 = xr[tid + 512];
    float s  = v0 + v1 + v2;
    float sq = v0 * v0 + v1 * v1 + v2 * v2;
#pragma unroll
    for (int off = 32; off; off >>= 1) {
        s  += __shfl_down(s, off);
        sq += __shfl_down(sq, off);
    }
    __shared__ float red1[4], red2[4];
    __shared__ float mean_s, rstd_s;
    int w = tid / 64, lane = tid % 64;
    if (lane == 0) { red1[w] = s; red2[w] = sq; }
    __syncthreads();
    if (tid == 0) {
        float S1 = red1[0] + red1[1] + red1[2] + red1[3];
        float S2 = red2[0] + red2[1] + red2[2] + red2[3];
        float m = S1 / (float)C_DIM;
        float var = S2 / (float)C_DIM - m * m;
        mean_s = m;
        rstd_s = rsqrtf(var + 1e-6f);
    }
    __syncthreads();
    float m = mean_s, r = rstd_s;
    yr[tid]       = (v0 - m) * r * g[tid]       + bta[tid];
    yr[tid + 256] = (v1 - m) * r * g[tid + 256] + bta[tid + 256];
    yr[tid + 512] = (v2 - m) * r * g[tid + 512] + bta[tid + 512];
}

// ---------------------------------------------------------------------------
// QKV split + RoPE + permute to (B, NH, S, DH).
// RoPE per reference: cos/sin table cos(s * invf[d%32]) (concat-style table)
// with interleaved-pair rotation rot[2i]=-t[2i+1], rot[2i+1]=t[2i].
// grid = B*NH*S blocks of 64 threads (one lane per d).
// ---------------------------------------------------------------------------
__global__ void rope_permute_kernel(const float* __restrict__ qkv,
                                    float* __restrict__ q, float* __restrict__ k,
                                    float* __restrict__ v) {
    int blk = blockIdx.x;
    int s = blk % S_LEN;
    int h = (blk / S_LEN) % NHEAD;
    int b = blk / (S_LEN * NHEAD);
    int d = threadIdx.x;

    const float* base = qkv + ((size_t)(b * S_LEN + s)) * (3 * C_DIM) + h * DHEAD + d;
    float qv = base[0];
    float kv = base[C_DIM];
    float vv = base[2 * C_DIM];

    float qp = __shfl_xor(qv, 1);
    float kp = __shfl_xor(kv, 1);
    float sign = (d & 1) ? 1.0f : -1.0f;   // even d: -t[d+1]; odd d: +t[d-1]

    float invf = expf(-((float)(2 * (d & 31)) / 64.0f) * 9.210340371976184f); // ln(10000)
    float ang = (float)s * invf;
    float c, sn;
    __sincosf(ang, &sn, &c);   // fast, but check accuracy; fallback below if needed
    // use accurate versions (range up to ~800 rad):
    c = cosf(ang);
    sn = sinf(ang);

    size_t o = ((size_t)(b * NHEAD + h) * S_LEN + s) * DHEAD + d;
    q[o] = qv * c + sign * qp * sn;
    k[o] = kv * c + sign * kp * sn;
    v[o] = vv;
}

// ---------------------------------------------------------------------------
// Attention: one block (256 thr) per (b, h, 4-row group). Full softmax(S=800).
// Writes directly to (B, S, C) layout.
// ---------------------------------------------------------------------------
__global__ __launch_bounds__(256)
void attn_kernel(const float* __restrict__ q, const float* __restrict__ k,
                 const float* __restrict__ v, float* __restrict__ o) {
    int blk = blockIdx.x;                      // 48 * 200
    int sb = blk % (S_LEN / 4);
    int bh = blk / (S_LEN / 4);
    int s0 = sb * 4;
    int b = bh / NHEAD, h = bh % NHEAD;

    const float* qbase = q + ((size_t)bh * S_LEN + s0) * DHEAD;
    const float* kbase = k + (size_t)bh * S_LEN * DHEAD;
    const float* vbase = v + (size_t)bh * S_LEN * DHEAD;

    __shared__ float qs[4][DHEAD];
    __shared__ float ps[4][S_LEN];
    __shared__ float lsum[4];
    __shared__ float opart[4][4][DHEAD];

    int tid = threadIdx.x;
    {
        int r = tid / 64, d = tid % 64;
        qs[r][d] = qbase[r * DHEAD + d];
    }
    __syncthreads();

    // scores: idx -> r = idx&3, t = idx>>2  (4 consecutive lanes share a k-row)
    for (int idx = tid; idx < 4 * S_LEN; idx += 256) {
        int r = idx & 3, t = idx >> 2;
        const float4* kr = (const float4*)(kbase + (size_t)t * DHEAD);
        const float4* qr = (const float4*)qs[r];
        float acc = 0.0f;
#pragma unroll
        for (int u = 0; u < 16; ++u) {
            float4 kv4 = kr[u];
            float4 qv4 = qr[u];
            acc += kv4.x * qv4.x + kv4.y * qv4.y + kv4.z * qv4.z + kv4.w * qv4.w;
        }
        ps[r][t] = acc * 0.125f;   // scale = DH^-0.5
    }
    __syncthreads();

    // per-row softmax, wave w handles row r=w
    int w = tid / 64, lane = tid % 64;
    {
        int r = w;
        float mx = -1e30f;
        for (int t = lane; t < S_LEN; t += 64) mx = fmaxf(mx, ps[r][t]);
#pragma unroll
        for (int off = 32; off; off >>= 1) mx = fmaxf(mx, __shfl_xor(mx, off));
        float sum = 0.0f;
        for (int t = lane; t < S_LEN; t += 64) {
            float e = expf(ps[r][t] - mx);
            ps[r][t] = e;
            sum += e;
        }
#pragma unroll
        for (int off = 32; off; off >>= 1) sum += __shfl_xor(sum, off);
        if (lane == 0) lsum[r] = sum;
    }
    __syncthreads();

    // PV: wave w handles t in [w*200, w*200+200), lane = d
    float oacc[4] = {0.0f, 0.0f, 0.0f, 0.0f};
    for (int t = w * 200; t < w * 200 + 200; ++t) {
        float vv = vbase[(size_t)t * DHEAD + lane];
#pragma unroll
        for (int r = 0; r < 4; ++r) oacc[r] += ps[r][t] * vv;
    }
#pragma unroll
    for (int r = 0; r < 4; ++r) opart[w][r][lane] = oacc[r];
    __syncthreads();

    {
        int r = tid / 64, d = tid % 64;
        float sum = opart[0][r][d] + opart[1][r][d] + opart[2][r][d] + opart[3][r][d];
        o[((size_t)(b * S_LEN + s0 + r)) * C_DIM + h * DHEAD + d] = sum / lsum[r];
    }
}

// ---------------------------------------------------------------------------
// Host launcher
// ---------------------------------------------------------------------------
extern "C" void kernel_launch(void* const* d_in, const int* in_sizes, int n_in,
                              void* d_out, int out_size, void* d_ws, size_t ws_size,
                              hipStream_t stream) {
    const float* x      = (const float*)d_in[0];
    const float* conv_w = (const float*)d_in[1];
    const float* conv_b = (const float*)d_in[2];
    const float* ln1_g  = (const float*)d_in[3];
    const float* ln1_b  = (const float*)d_in[4];
    const float* qkv_w  = (const float*)d_in[5];
    const float* qkv_b  = (const float*)d_in[6];
    const float* proj_w = (const float*)d_in[7];
    const float* proj_b = (const float*)d_in[8];
    const float* ln2_g  = (const float*)d_in[9];
    const float* ln2_b  = (const float*)d_in[10];
    const float* fc1_w  = (const float*)d_in[11];
    const float* fc1_b  = (const float*)d_in[12];
    const float* fc2_w  = (const float*)d_in[13];
    const float* fc2_b  = (const float*)d_in[14];
    const float* lnf_g  = (const float*)d_in[15];
    const float* lnf_b  = (const float*)d_in[16];

    float* ws = (float*)d_ws;
    const size_t NTC = (size_t)NTOK * C_DIM;          // 2,457,600
    float* h   = ws;                                  // (B,S,C)
    float* y   = h + NTC;                             // (B,S,C)  ln out / attn out
    float* big = y + NTC;                             // qkv (B,S,3C) / mlp hidden / im2col
    float* qb  = big + (size_t)NTOK * HID_DIM;        // (B,NH,S,DH)
    float* kb  = qb + NTC;
    float* vb  = kb + NTC;
    float* wT  = vb + NTC;                            // (768,768)

    // patch embed
    transpose_w_kernel<<<(768 * 768 + 255) / 256, 256, 0, stream>>>(conv_w, wT);
    im2col_kernel<<<(NTOK * 768 + 255) / 256, 256, 0, stream>>>(x, big);
    gemm_kernel<false, false><<<dim3(C_DIM / 64, NTOK / 64), 256, 0, stream>>>(
        big, wT, conv_b, nullptr, h, NTOK, C_DIM, 768);

    for (int l = 0; l < DEPTH_N; ++l) {
        const float* l1g = ln1_g + (size_t)l * C_DIM;
        const float* l1b = ln1_b + (size_t)l * C_DIM;
        const float* qw  = qkv_w + (size_t)l * C_DIM * 3 * C_DIM;
        const float* qbs = qkv_b + (size_t)l * 3 * C_DIM;
        const float* pw  = proj_w + (size_t)l * C_DIM * C_DIM;
        const float* pb  = proj_b + (size_t)l * C_DIM;
        const float* l2g = ln2_g + (size_t)l * C_DIM;
        const float* l2b = ln2_b + (size_t)l * C_DIM;
        const float* f1w = fc1_w + (size_t)l * C_DIM * HID_DIM;
        const float* f1b = fc1_b + (size_t)l * HID_DIM;
        const float* f2w = fc2_w + (size_t)l * HID_DIM * C_DIM;
        const float* f2b = fc2_b + (size_t)l * C_DIM;

        ln_kernel<<<NTOK, 256, 0, stream>>>(h, l1g, l1b, y);
        gemm_kernel<false, false><<<dim3(3 * C_DIM / 64, NTOK / 64), 256, 0, stream>>>(
            y, qw, qbs, nullptr, big, NTOK, 3 * C_DIM, C_DIM);
        rope_permute_kernel<<<BATCH * NHEAD * S_LEN, 64, 0, stream>>>(big, qb, kb, vb);
        attn_kernel<<<BATCH * NHEAD * (S_LEN / 4), 256, 0, stream>>>(qb, kb, vb, y);
        gemm_kernel<false, true><<<dim3(C_DIM / 64, NTOK / 64), 256, 0, stream>>>(
            y, pw, pb, h, h, NTOK, C_DIM, C_DIM);
        ln_kernel<<<NTOK, 256, 0, stream>>>(h, l2g, l2b, y);
        gemm_kernel<true, false><<<dim3(HID_DIM / 64, NTOK / 64), 256, 0, stream>>>(
            y, f1w, f1b, nullptr, big, NTOK, HID_DIM, C_DIM);
        gemm_kernel<false, true><<<dim3(C_DIM / 64, NTOK / 64), 256, 0, stream>>>(
            big, f2w, f2b, h, h, NTOK, C_DIM, HID_DIM);
    }

    ln_kernel<<<NTOK, 256, 0, stream>>>(h, lnf_g, lnf_b, (float*)d_out);
}

// Round 2
// 5789.286 us; speedup vs baseline: 2.1718x; 2.1718x over previous
//
#include <hip/hip_runtime.h>
#include <hip/hip_bf16.h>
#include <math.h>

#define S_LEN   800
#define C_DIM   768
#define NHEAD   12
#define DHEAD   64
#define HID_DIM 3072
#define BATCH   4
#define NTOK    (BATCH * S_LEN)   // 3200
#define DEPTH_N 12

using bf16x8 = __attribute__((ext_vector_type(8))) short;
using f32x4  = __attribute__((ext_vector_type(4))) float;

__device__ inline short f2bf(float x) {
    unsigned u = __builtin_bit_cast(unsigned, x);
    u += 0x7fff + ((u >> 16) & 1);          // RNE
    return (short)(u >> 16);
}

typedef const __attribute__((address_space(1))) void* gas_ptr;
typedef __attribute__((address_space(3))) void* las_ptr;
__device__ inline void async_copy16(const void* g, void* l) {
    __builtin_amdgcn_global_load_lds((gas_ptr)g, (las_ptr)l, 16, 0, 0);
}

// ---------------------------------------------------------------------------
// Transpose + convert: W fp32 [K][N] -> Wt bf16 [N][K]
// ---------------------------------------------------------------------------
__global__ __launch_bounds__(256)
void transpose_convert_kernel(const float* __restrict__ W, short* __restrict__ Wt,
                              int K, int N) {
    __shared__ float tile[32][33];
    int k0 = blockIdx.y * 32, n0 = blockIdx.x * 32;
    int tx = threadIdx.x & 31, ty = threadIdx.x >> 5;   // 32 x 8
#pragma unroll
    for (int i = ty; i < 32; i += 8)
        tile[i][tx] = W[(size_t)(k0 + i) * N + n0 + tx];
    __syncthreads();
#pragma unroll
    for (int i = ty; i < 32; i += 8)
        Wt[(size_t)(n0 + i) * K + k0 + tx] = f2bf(tile[tx][i]);
}

// conv_w (O,K) is already [N][K] for the embed GEMM -> elementwise convert only
__global__ void convert_bf_kernel(const float* __restrict__ a, short* __restrict__ o, int n) {
    int i = blockIdx.x * 256 + threadIdx.x;
    if (i < n) o[i] = f2bf(a[i]);
}

// ---------------------------------------------------------------------------
// im2col (bf16 out) for the dual patch embed.
// ---------------------------------------------------------------------------
__global__ void im2col_kernel(const float* __restrict__ x, short* __restrict__ A) {
    int idx = blockIdx.x * 256 + threadIdx.x;          // 3200*768
    if (idx >= NTOK * 768) return;
    int kk = idx % 768;
    int s  = (idx / 768) % S_LEN;
    int b  = idx / (768 * S_LEN);
    int c  = kk / 256;
    int i  = (kk / 16) % 16;
    int j  = kk % 16;
    int half = s / 400, ss = s % 400;
    int hg = ss / 20, wg = ss % 20;
    int ch = half * 3 + c;
    A[idx] = f2bf(x[((size_t)(b * 6 + ch) * 320 + hg * 16 + i) * 320 + wg * 16 + j]);
}

// ---------------------------------------------------------------------------
// bf16 MFMA GEMM: C[M,N] = A[M,K](bf16) @ Bt[N,K](bf16)^T + bias (+res)(+GELU)
// BM=128, BK=32, 256 threads (4 waves). BN=128: wave=64x64 (4x4 MFMA tiles);
// BN=64: wave=32x64 (2x4). global_load_lds width-16 staging.
// M%128==0, N%BN==0, K%32==0 for all calls here.
// ---------------------------------------------------------------------------
template <int BN, bool GELU, bool RES, bool OBF>
__global__ __launch_bounds__(256)
void gemm_mfma(const short* __restrict__ A, const short* __restrict__ Bt,
               const float* __restrict__ bias, const float* __restrict__ res,
               void* __restrict__ Cout, int M, int N, int K) {
    constexpr int BM = 128, BK = 32;
    constexpr int TI = (BN == 128) ? 4 : 2;     // A tiles per wave
    constexpr int TJ = 4;                       // B tiles per wave
    constexpr int ACALLS = BM * BK / (8 * 64);  // 16B chunks / 64 lanes = 8
    constexpr int BCALLS = BN * BK / (8 * 64);  // 8 or 4

    __shared__ short As[BM * BK];   // [m][k], k inner, contiguous (global_load_lds order)
    __shared__ short Bs[BN * BK];   // [n][k]

    int tid = threadIdx.x;
    int w = tid >> 6, lane = tid & 63;
    int m0 = blockIdx.y * BM, n0 = blockIdx.x * BN;

    int wr = (BN == 128) ? (w >> 1) * 64 : w * 32;
    int wc = (BN == 128) ? (w & 1) * 64 : 0;

    f32x4 acc[TI][TJ];
#pragma unroll
    for (int i = 0; i < TI; ++i)
#pragma unroll
        for (int j = 0; j < TJ; ++j)
            acc[i][j] = (f32x4){0.f, 0.f, 0.f, 0.f};

    int mrow = wr + (lane & 15);
    int ncol = wc + (lane & 15);
    int kq = (lane >> 4) * 8;

    for (int k0 = 0; k0 < K; k0 += BK) {
        // stage A: chunk c = j*64+lane -> row c>>2, k-chunk (c&3)*8
#pragma unroll
        for (int j = w; j < ACALLS; j += 4) {
            int c = j * 64 + lane;
            int row = c >> 2, kc = (c & 3) * 8;
            async_copy16(A + (size_t)(m0 + row) * K + k0 + kc, As + j * 512);
        }
#pragma unroll
        for (int j = w; j < BCALLS; j += 4) {
            int c = j * 64 + lane;
            int row = c >> 2, kc = (c & 3) * 8;
            async_copy16(Bt + (size_t)(n0 + row) * K + k0 + kc, Bs + j * 512);
        }
        __syncthreads();

        bf16x8 afrag[TI], bfrag[TJ];
#pragma unroll
        for (int i = 0; i < TI; ++i)
            afrag[i] = *(const bf16x8*)(As + (mrow + i * 16) * BK + kq);
#pragma unroll
        for (int j = 0; j < TJ; ++j)
            bfrag[j] = *(const bf16x8*)(Bs + (ncol + j * 16) * BK + kq);
#pragma unroll
        for (int i = 0; i < TI; ++i)
#pragma unroll
            for (int j = 0; j < TJ; ++j)
                acc[i][j] = __builtin_amdgcn_mfma_f32_16x16x32_bf16(
                    afrag[i], bfrag[j], acc[i][j], 0, 0, 0);
        __syncthreads();
    }

    // epilogue: C/D mapping col=lane&15, row=(lane>>4)*4+reg
    int col = lane & 15;
    int rbase = (lane >> 4) * 4;
#pragma unroll
    for (int i = 0; i < TI; ++i)
#pragma unroll
        for (int j = 0; j < TJ; ++j)
#pragma unroll
            for (int r = 0; r < 4; ++r) {
                int m = m0 + wr + i * 16 + rbase + r;
                int n = n0 + wc + j * 16 + col;
                float v = acc[i][j][r] + bias[n];
                if (RES) v += res[(size_t)m * N + n];
                if (GELU) v = 0.5f * v * (1.0f + erff(v * 0.70710678118654752f));
                if (OBF) ((short*)Cout)[(size_t)m * N + n] = f2bf(v);
                else     ((float*)Cout)[(size_t)m * N + n] = v;
            }
}

// ---------------------------------------------------------------------------
// LayerNorm: one block (256 thr) per row of 768. OBF -> bf16 output.
// ---------------------------------------------------------------------------
template <bool OBF>
__global__ __launch_bounds__(256)
void ln_kernel(const float* __restrict__ x, const float* __restrict__ g,
               const float* __restrict__ bta, void* __restrict__ yv) {
    int row = blockIdx.x;
    const float* xr = x + (size_t)row * C_DIM;
    int tid = threadIdx.x;

    float v0 = xr[tid], v1 = xr[tid + 256], v2 = xr[tid + 512];
    float s  = v0 + v1 + v2;
    float sq = v0 * v0 + v1 * v1 + v2 * v2;
#pragma unroll
    for (int off = 32; off; off >>= 1) {
        s  += __shfl_down(s, off);
        sq += __shfl_down(sq, off);
    }
    __shared__ float red1[4], red2[4];
    __shared__ float mean_s, rstd_s;
    int wv = tid / 64, lane = tid % 64;
    if (lane == 0) { red1[wv] = s; red2[wv] = sq; }
    __syncthreads();
    if (tid == 0) {
        float S1 = red1[0] + red1[1] + red1[2] + red1[3];
        float S2 = red2[0] + red2[1] + red2[2] + red2[3];
        float m = S1 / (float)C_DIM;
        float var = S2 / (float)C_DIM - m * m;
        mean_s = m;
        rstd_s = rsqrtf(var + 1e-6f);
    }
    __syncthreads();
    float m = mean_s, r = rstd_s;
    float o0 = (v0 - m) * r * g[tid]       + bta[tid];
    float o1 = (v1 - m) * r * g[tid + 256] + bta[tid + 256];
    float o2 = (v2 - m) * r * g[tid + 512] + bta[tid + 512];
    if (OBF) {
        short* yr = (short*)yv + (size_t)row * C_DIM;
        yr[tid] = f2bf(o0); yr[tid + 256] = f2bf(o1); yr[tid + 512] = f2bf(o2);
    } else {
        float* yr = (float*)yv + (size_t)row * C_DIM;
        yr[tid] = o0; yr[tid + 256] = o1; yr[tid + 512] = o2;
    }
}

// ---------------------------------------------------------------------------
// QKV split + RoPE + permute to (B, NH, S, DH), fp32.
// ---------------------------------------------------------------------------
__global__ void rope_permute_kernel(const float* __restrict__ qkv,
                                    float* __restrict__ q, float* __restrict__ k,
                                    float* __restrict__ v) {
    int blk = blockIdx.x;
    int s = blk % S_LEN;
    int h = (blk / S_LEN) % NHEAD;
    int b = blk / (S_LEN * NHEAD);
    int d = threadIdx.x;

    const float* base = qkv + ((size_t)(b * S_LEN + s)) * (3 * C_DIM) + h * DHEAD + d;
    float qv = base[0];
    float kv = base[C_DIM];
    float vv = base[2 * C_DIM];

    float qp = __shfl_xor(qv, 1);
    float kp = __shfl_xor(kv, 1);
    float sign = (d & 1) ? 1.0f : -1.0f;

    float invf = expf(-((float)(2 * (d & 31)) / 64.0f) * 9.210340371976184f); // ln(10000)
    float ang = (float)s * invf;
    float c = cosf(ang);
    float sn = sinf(ang);

    size_t o = ((size_t)(b * NHEAD + h) * S_LEN + s) * DHEAD + d;
    q[o] = qv * c + sign * qp * sn;
    k[o] = kv * c + sign * kp * sn;
    v[o] = vv;
}

// ---------------------------------------------------------------------------
// Attention: one block (256 thr) per (b, h, 4-row group). bf16 output.
// ---------------------------------------------------------------------------
__global__ __launch_bounds__(256)
void attn_kernel(const float* __restrict__ q, const float* __restrict__ k,
                 const float* __restrict__ v, short* __restrict__ o) {
    int blk = blockIdx.x;                      // 48 * 200
    int sb = blk % (S_LEN / 4);
    int bh = blk / (S_LEN / 4);
    int s0 = sb * 4;
    int b = bh / NHEAD, h = bh % NHEAD;

    const float* qbase = q + ((size_t)bh * S_LEN + s0) * DHEAD;
    const float* kbase = k + (size_t)bh * S_LEN * DHEAD;
    const float* vbase = v + (size_t)bh * S_LEN * DHEAD;

    __shared__ float qs[4][DHEAD];
    __shared__ float ps[4][S_LEN];
    __shared__ float lsum[4];
    __shared__ float opart[4][4][DHEAD];

    int tid = threadIdx.x;
    {
        int r = tid / 64, d = tid % 64;
        qs[r][d] = qbase[r * DHEAD + d];
    }
    __syncthreads();

    for (int idx = tid; idx < 4 * S_LEN; idx += 256) {
        int r = idx & 3, t = idx >> 2;
        const float4* kr = (const float4*)(kbase + (size_t)t * DHEAD);
        const float4* qr = (const float4*)qs[r];
        float acc = 0.0f;
#pragma unroll
        for (int u = 0; u < 16; ++u) {
            float4 kv4 = kr[u];
            float4 qv4 = qr[u];
            acc += kv4.x * qv4.x + kv4.y * qv4.y + kv4.z * qv4.z + kv4.w * qv4.w;
        }
        ps[r][t] = acc * 0.125f;
    }
    __syncthreads();

    int w = tid / 64, lane = tid % 64;
    {
        int r = w;
        float mx = -1e30f;
        for (int t = lane; t < S_LEN; t += 64) mx = fmaxf(mx, ps[r][t]);
#pragma unroll
        for (int off = 32; off; off >>= 1) mx = fmaxf(mx, __shfl_xor(mx, off));
        float sum = 0.0f;
        for (int t = lane; t < S_LEN; t += 64) {
            float e = expf(ps[r][t] - mx);
            ps[r][t] = e;
            sum += e;
        }
#pragma unroll
        for (int off = 32; off; off >>= 1) sum += __shfl_xor(sum, off);
        if (lane == 0) lsum[r] = sum;
    }
    __syncthreads();

    float oacc[4] = {0.0f, 0.0f, 0.0f, 0.0f};
    for (int t = w * 200; t < w * 200 + 200; ++t) {
        float vv = vbase[(size_t)t * DHEAD + lane];
#pragma unroll
        for (int r = 0; r < 4; ++r) oacc[r] += ps[r][t] * vv;
    }
#pragma unroll
    for (int r = 0; r < 4; ++r) opart[w][r][lane] = oacc[r];
    __syncthreads();

    {
        int r = tid / 64, d = tid % 64;
        float sum = opart[0][r][d] + opart[1][r][d] + opart[2][r][d] + opart[3][r][d];
        o[((size_t)(b * S_LEN + s0 + r)) * C_DIM + h * DHEAD + d] = f2bf(sum / lsum[r]);
    }
}

// ---------------------------------------------------------------------------
// Host launcher
// ---------------------------------------------------------------------------
extern "C" void kernel_launch(void* const* d_in, const int* in_sizes, int n_in,
                              void* d_out, int out_size, void* d_ws, size_t ws_size,
                              hipStream_t stream) {
    const float* x      = (const float*)d_in[0];
    const float* conv_w = (const float*)d_in[1];
    const float* conv_b = (const float*)d_in[2];
    const float* ln1_g  = (const float*)d_in[3];
    const float* ln1_b  = (const float*)d_in[4];
    const float* qkv_w  = (const float*)d_in[5];
    const float* qkv_b  = (const float*)d_in[6];
    const float* proj_w = (const float*)d_in[7];
    const float* proj_b = (const float*)d_in[8];
    const float* ln2_g  = (const float*)d_in[9];
    const float* ln2_b  = (const float*)d_in[10];
    const float* fc1_w  = (const float*)d_in[11];
    const float* fc1_b  = (const float*)d_in[12];
    const float* fc2_w  = (const float*)d_in[13];
    const float* fc2_b  = (const float*)d_in[14];
    const float* lnf_g  = (const float*)d_in[15];
    const float* lnf_b  = (const float*)d_in[16];

    const size_t NTC = (size_t)NTOK * C_DIM;          // 2,457,600
    float* ws = (float*)d_ws;
    float* h       = ws;                              // (B,S,C) f32
    float* qkv_out = h + NTC;                         // (B,S,3C) f32
    float* qb      = qkv_out + (size_t)NTOK * 3 * C_DIM;
    float* kb      = qb + NTC;
    float* vb      = kb + NTC;
    short* y_bf    = (short*)(vb + NTC);              // (B,S,C) bf16
    short* big_bf  = y_bf + NTC;                      // (B,S,HID) bf16 / im2col
    short* wbuf    = big_bf + (size_t)NTOK * HID_DIM; // max 3072*768 bf16
    short* embed_wt = wbuf + (size_t)HID_DIM * C_DIM; // 768*768 bf16

    // ---- patch embed ----
    convert_bf_kernel<<<(768 * 768 + 255) / 256, 256, 0, stream>>>(conv_w, embed_wt, 768 * 768);
    im2col_kernel<<<(NTOK * 768 + 255) / 256, 256, 0, stream>>>(x, big_bf);
    gemm_mfma<64, false, false, false><<<dim3(C_DIM / 64, NTOK / 128), 256, 0, stream>>>(
        big_bf, embed_wt, conv_b, nullptr, h, NTOK, C_DIM, C_DIM);

    for (int l = 0; l < DEPTH_N; ++l) {
        const float* l1g = ln1_g + (size_t)l * C_DIM;
        const float* l1b = ln1_b + (size_t)l * C_DIM;
        const float* qw  = qkv_w + (size_t)l * C_DIM * 3 * C_DIM;
        const float* qbs = qkv_b + (size_t)l * 3 * C_DIM;
        const float* pw  = proj_w + (size_t)l * C_DIM * C_DIM;
        const float* pb  = proj_b + (size_t)l * C_DIM;
        const float* l2g = ln2_g + (size_t)l * C_DIM;
        const float* l2b = ln2_b + (size_t)l * C_DIM;
        const float* f1w = fc1_w + (size_t)l * C_DIM * HID_DIM;
        const float* f1b = fc1_b + (size_t)l * HID_DIM;
        const float* f2w = fc2_w + (size_t)l * HID_DIM * C_DIM;
        const float* f2b = fc2_b + (size_t)l * C_DIM;

        // qkv
        ln_kernel<true><<<NTOK, 256, 0, stream>>>(h, l1g, l1b, y_bf);
        transpose_convert_kernel<<<dim3(3 * C_DIM / 32, C_DIM / 32), 256, 0, stream>>>(
            qw, wbuf, C_DIM, 3 * C_DIM);
        gemm_mfma<128, false, false, false><<<dim3(3 * C_DIM / 128, NTOK / 128), 256, 0, stream>>>(
            y_bf, wbuf, qbs, nullptr, qkv_out, NTOK, 3 * C_DIM, C_DIM);

        // attention
        rope_permute_kernel<<<BATCH * NHEAD * S_LEN, 64, 0, stream>>>(qkv_out, qb, kb, vb);
        attn_kernel<<<BATCH * NHEAD * (S_LEN / 4), 256, 0, stream>>>(qb, kb, vb, y_bf);

        // proj (+res into h)
        transpose_convert_kernel<<<dim3(C_DIM / 32, C_DIM / 32), 256, 0, stream>>>(
            pw, wbuf, C_DIM, C_DIM);
        gemm_mfma<64, false, true, false><<<dim3(C_DIM / 64, NTOK / 128), 256, 0, stream>>>(
            y_bf, wbuf, pb, h, h, NTOK, C_DIM, C_DIM);

        // mlp
        ln_kernel<true><<<NTOK, 256, 0, stream>>>(h, l2g, l2b, y_bf);
        transpose_convert_kernel<<<dim3(HID_DIM / 32, C_DIM / 32), 256, 0, stream>>>(
            f1w, wbuf, C_DIM, HID_DIM);
        gemm_mfma<128, true, false, true><<<dim3(HID_DIM / 128, NTOK / 128), 256, 0, stream>>>(
            y_bf, wbuf, f1b, nullptr, big_bf, NTOK, HID_DIM, C_DIM);
        transpose_convert_kernel<<<dim3(C_DIM / 32, HID_DIM / 32), 256, 0, stream>>>(
            f2w, wbuf, HID_DIM, C_DIM);
        gemm_mfma<64, false, true, false><<<dim3(C_DIM / 64, NTOK / 128), 256, 0, stream>>>(
            big_bf, wbuf, f2b, h, h, NTOK, C_DIM, HID_DIM);
    }

    ln_kernel<false><<<NTOK, 256, 0, stream>>>(h, lnf_g, lnf_b, d_out);
}

// Round 3
// 2990.177 us; speedup vs baseline: 4.2048x; 1.9361x over previous
//
#include <hip/hip_runtime.h>
#include <hip/hip_bf16.h>
#include <math.h>

#define S_LEN   800
#define SP_LEN  832              // padded to 13*64
#define C_DIM   768
#define NHEAD   12
#define DHEAD   64
#define HID_DIM 3072
#define BATCH   4
#define NTOK    (BATCH * S_LEN)   // 3200
#define DEPTH_N 12

using bf16x8 = __attribute__((ext_vector_type(8))) short;
using f32x4  = __attribute__((ext_vector_type(4))) float;

__device__ inline short f2bf(float x) {
    unsigned u = __builtin_bit_cast(unsigned, x);
    u += 0x7fff + ((u >> 16) & 1);          // RNE
    return (short)(u >> 16);
}

typedef const __attribute__((address_space(1))) void* gas_ptr;
typedef __attribute__((address_space(3))) void* las_ptr;
__device__ inline void async_copy16(const void* g, void* l) {
    __builtin_amdgcn_global_load_lds((gas_ptr)g, (las_ptr)l, 16, 0, 0);
}

// ---------------------------------------------------------------------------
// Transpose + convert: W fp32 [K][N] -> Wt bf16 [N][K]
// ---------------------------------------------------------------------------
__global__ __launch_bounds__(256)
void transpose_convert_kernel(const float* __restrict__ W, short* __restrict__ Wt,
                              int K, int N) {
    __shared__ float tile[32][33];
    int k0 = blockIdx.y * 32, n0 = blockIdx.x * 32;
    int tx = threadIdx.x & 31, ty = threadIdx.x >> 5;   // 32 x 8
#pragma unroll
    for (int i = ty; i < 32; i += 8)
        tile[i][tx] = W[(size_t)(k0 + i) * N + n0 + tx];
    __syncthreads();
#pragma unroll
    for (int i = ty; i < 32; i += 8)
        Wt[(size_t)(n0 + i) * K + k0 + tx] = f2bf(tile[tx][i]);
}

__global__ void convert_bf_kernel(const float* __restrict__ a, short* __restrict__ o, int n) {
    int i = blockIdx.x * 256 + threadIdx.x;
    if (i < n) o[i] = f2bf(a[i]);
}

// ---------------------------------------------------------------------------
// im2col (bf16 out) for the dual patch embed.
// ---------------------------------------------------------------------------
__global__ void im2col_kernel(const float* __restrict__ x, short* __restrict__ A) {
    int idx = blockIdx.x * 256 + threadIdx.x;          // 3200*768
    if (idx >= NTOK * 768) return;
    int kk = idx % 768;
    int s  = (idx / 768) % S_LEN;
    int b  = idx / (768 * S_LEN);
    int c  = kk / 256;
    int i  = (kk / 16) % 16;
    int j  = kk % 16;
    int half = s / 400, ss = s % 400;
    int hg = ss / 20, wg = ss % 20;
    int ch = half * 3 + c;
    A[idx] = f2bf(x[((size_t)(b * 6 + ch) * 320 + hg * 16 + i) * 320 + wg * 16 + j]);
}

// ---------------------------------------------------------------------------
// bf16 MFMA GEMM (unchanged from round 2)
// ---------------------------------------------------------------------------
template <int BN, bool GELU, bool RES, bool OBF>
__global__ __launch_bounds__(256)
void gemm_mfma(const short* __restrict__ A, const short* __restrict__ Bt,
               const float* __restrict__ bias, const float* __restrict__ res,
               void* __restrict__ Cout, int M, int N, int K) {
    constexpr int BM = 128, BK = 32;
    constexpr int TI = (BN == 128) ? 4 : 2;
    constexpr int TJ = 4;
    constexpr int ACALLS = BM * BK / (8 * 64);
    constexpr int BCALLS = BN * BK / (8 * 64);

    __shared__ short As[BM * BK];
    __shared__ short Bs[BN * BK];

    int tid = threadIdx.x;
    int w = tid >> 6, lane = tid & 63;
    int m0 = blockIdx.y * BM, n0 = blockIdx.x * BN;

    int wr = (BN == 128) ? (w >> 1) * 64 : w * 32;
    int wc = (BN == 128) ? (w & 1) * 64 : 0;

    f32x4 acc[TI][TJ];
#pragma unroll
    for (int i = 0; i < TI; ++i)
#pragma unroll
        for (int j = 0; j < TJ; ++j)
            acc[i][j] = (f32x4){0.f, 0.f, 0.f, 0.f};

    int mrow = wr + (lane & 15);
    int ncol = wc + (lane & 15);
    int kq = (lane >> 4) * 8;

    for (int k0 = 0; k0 < K; k0 += BK) {
#pragma unroll
        for (int j = w; j < ACALLS; j += 4) {
            int c = j * 64 + lane;
            int row = c >> 2, kc = (c & 3) * 8;
            async_copy16(A + (size_t)(m0 + row) * K + k0 + kc, As + j * 512);
        }
#pragma unroll
        for (int j = w; j < BCALLS; j += 4) {
            int c = j * 64 + lane;
            int row = c >> 2, kc = (c & 3) * 8;
            async_copy16(Bt + (size_t)(n0 + row) * K + k0 + kc, Bs + j * 512);
        }
        __syncthreads();

        bf16x8 afrag[TI], bfrag[TJ];
#pragma unroll
        for (int i = 0; i < TI; ++i)
            afrag[i] = *(const bf16x8*)(As + (mrow + i * 16) * BK + kq);
#pragma unroll
        for (int j = 0; j < TJ; ++j)
            bfrag[j] = *(const bf16x8*)(Bs + (ncol + j * 16) * BK + kq);
#pragma unroll
        for (int i = 0; i < TI; ++i)
#pragma unroll
            for (int j = 0; j < TJ; ++j)
                acc[i][j] = __builtin_amdgcn_mfma_f32_16x16x32_bf16(
                    afrag[i], bfrag[j], acc[i][j], 0, 0, 0);
        __syncthreads();
    }

    int col = lane & 15;
    int rbase = (lane >> 4) * 4;
#pragma unroll
    for (int i = 0; i < TI; ++i)
#pragma unroll
        for (int j = 0; j < TJ; ++j)
#pragma unroll
            for (int r = 0; r < 4; ++r) {
                int m = m0 + wr + i * 16 + rbase + r;
                int n = n0 + wc + j * 16 + col;
                float v = acc[i][j][r] + bias[n];
                if (RES) v += res[(size_t)m * N + n];
                if (GELU) v = 0.5f * v * (1.0f + erff(v * 0.70710678118654752f));
                if (OBF) ((short*)Cout)[(size_t)m * N + n] = f2bf(v);
                else     ((float*)Cout)[(size_t)m * N + n] = v;
            }
}

// ---------------------------------------------------------------------------
// LayerNorm (unchanged)
// ---------------------------------------------------------------------------
template <bool OBF>
__global__ __launch_bounds__(256)
void ln_kernel(const float* __restrict__ x, const float* __restrict__ g,
               const float* __restrict__ bta, void* __restrict__ yv) {
    int row = blockIdx.x;
    const float* xr = x + (size_t)row * C_DIM;
    int tid = threadIdx.x;

    float v0 = xr[tid], v1 = xr[tid + 256], v2 = xr[tid + 512];
    float s  = v0 + v1 + v2;
    float sq = v0 * v0 + v1 * v1 + v2 * v2;
#pragma unroll
    for (int off = 32; off; off >>= 1) {
        s  += __shfl_down(s, off);
        sq += __shfl_down(sq, off);
    }
    __shared__ float red1[4], red2[4];
    __shared__ float mean_s, rstd_s;
    int wv = tid / 64, lane = tid % 64;
    if (lane == 0) { red1[wv] = s; red2[wv] = sq; }
    __syncthreads();
    if (tid == 0) {
        float S1 = red1[0] + red1[1] + red1[2] + red1[3];
        float S2 = red2[0] + red2[1] + red2[2] + red2[3];
        float m = S1 / (float)C_DIM;
        float var = S2 / (float)C_DIM - m * m;
        mean_s = m;
        rstd_s = rsqrtf(var + 1e-6f);
    }
    __syncthreads();
    float m = mean_s, r = rstd_s;
    float o0 = (v0 - m) * r * g[tid]       + bta[tid];
    float o1 = (v1 - m) * r * g[tid + 256] + bta[tid + 256];
    float o2 = (v2 - m) * r * g[tid + 512] + bta[tid + 512];
    if (OBF) {
        short* yr = (short*)yv + (size_t)row * C_DIM;
        yr[tid] = f2bf(o0); yr[tid + 256] = f2bf(o1); yr[tid + 512] = f2bf(o2);
    } else {
        float* yr = (float*)yv + (size_t)row * C_DIM;
        yr[tid] = o0; yr[tid + 256] = o1; yr[tid + 512] = o2;
    }
}

// ---------------------------------------------------------------------------
// RoPE + split + bf16 convert.
//   qb: (bh, s[832], dh) bf16, q pre-scaled by 0.125*log2(e)
//   kb: (bh, s[832], dh) bf16
//   vtb: (bh, dh, s[832]) bf16  (transposed for PV B-fragments)
// Pad rows (s>=800) zeroed. grid (13, 48), 256 thr.
// ---------------------------------------------------------------------------
__global__ __launch_bounds__(256)
void rope_qkv_kernel(const float* __restrict__ qkv, short* __restrict__ qb,
                     short* __restrict__ kb, short* __restrict__ vtb) {
    int st = blockIdx.x;           // 0..12
    int bh = blockIdx.y;           // 0..47
    int b = bh / NHEAD, h = bh % NHEAD;
    int s0 = st * 64;

    __shared__ short vlds[64][72];

    int tid = threadIdx.x;
    int sl = tid >> 2;             // 0..63  (s row within tile)
    int dc = (tid & 3) * 16;       // d chunk base
    int s = s0 + sl;

    short qo[16], ko[16];
    if (s < S_LEN) {
        const float* base = qkv + ((size_t)(b * S_LEN + s)) * (3 * C_DIM) + h * DHEAD + dc;
        float qv[16], kv[16];
#pragma unroll
        for (int i = 0; i < 16; ++i) { qv[i] = base[i]; kv[i] = base[C_DIM + i]; }
#pragma unroll
        for (int i = 0; i < 16; ++i) {
            int d = dc + i;
            float ang = (float)s * exp2f(-(float)(d & 31) * 0.41524101186092029f); // log2(1e4)/16
            float c = cosf(ang), sn = sinf(ang);
            float sign = (i & 1) ? 1.0f : -1.0f;
            qo[i] = f2bf((qv[i] * c + sign * qv[i ^ 1] * sn) * 0.18033688011112042f);
            ko[i] = f2bf(kv[i] * c + sign * kv[i ^ 1] * sn);
        }
#pragma unroll
        for (int i = 0; i < 16; ++i)
            vlds[sl][dc + i] = f2bf(base[2 * C_DIM + i]);
    } else {
#pragma unroll
        for (int i = 0; i < 16; ++i) { qo[i] = 0; ko[i] = 0; vlds[sl][dc + i] = 0; }
    }
    {
        short* qd = qb + ((size_t)bh * SP_LEN + s) * DHEAD + dc;
        short* kd = kb + ((size_t)bh * SP_LEN + s) * DHEAD + dc;
        *(bf16x8*)(qd)     = *(bf16x8*)(qo);
        *(bf16x8*)(qd + 8) = *(bf16x8*)(qo + 8);
        *(bf16x8*)(kd)     = *(bf16x8*)(ko);
        *(bf16x8*)(kd + 8) = *(bf16x8*)(ko + 8);
    }
    __syncthreads();
    // transposed v write: thread -> d row, 16 s values
    {
        int dr = tid >> 2, sc = (tid & 3) * 16;
        short vo[16];
#pragma unroll
        for (int i = 0; i < 16; ++i) vo[i] = vlds[sc + i][dr];
        short* vd = vtb + ((size_t)bh * DHEAD + dr) * SP_LEN + s0 + sc;
        *(bf16x8*)(vd)     = *(bf16x8*)(vo);
        *(bf16x8*)(vd + 8) = *(bf16x8*)(vo + 8);
    }
}

// ---------------------------------------------------------------------------
// Flash attention, bf16 MFMA. Block = 64 q-rows of one (b,h); 4 waves,
// each owns a 16-row strip. 13 key-tiles of 64 (last: 32 valid).
// Online softmax in base-2 domain (q pre-scaled by 0.125*log2e).
// Output bf16 (b, s, C).
// ---------------------------------------------------------------------------
__global__ __launch_bounds__(256)
void attn_mfma_kernel(const short* __restrict__ qb, const short* __restrict__ kb,
                      const short* __restrict__ vtb, short* __restrict__ o) {
    int qt = blockIdx.x;           // 0..12
    int bh = blockIdx.y;           // 0..47
    int b = bh / NHEAD, h = bh % NHEAD;
    int m0 = qt * 64;

    __shared__ short Qs[64 * 64];
    __shared__ short Ks[64 * 64];
    __shared__ short Vts[64 * 64];
    __shared__ short Ps[64 * 72];

    int tid = threadIdx.x;
    int w = tid >> 6, lane = tid & 63;
    int lc = lane & 15;            // col within 16-tile
    int lq = lane >> 4;            // quad
    int kq = lq * 8;

    const short* qbase = qb + (size_t)bh * SP_LEN * DHEAD;
    const short* kbase = kb + (size_t)bh * SP_LEN * DHEAD;
    const short* vbase = vtb + (size_t)bh * DHEAD * SP_LEN;

    f32x4 oacc[4];
#pragma unroll
    for (int t = 0; t < 4; ++t) oacc[t] = (f32x4){0.f, 0.f, 0.f, 0.f};
    float mrow[4] = {-3.0e38f, -3.0e38f, -3.0e38f, -3.0e38f};
    float lrow[4] = {0.f, 0.f, 0.f, 0.f};

    // stage Q once (contiguous 64x64 tile)
#pragma unroll
    for (int j = w; j < 8; j += 4)
        async_copy16(qbase + (size_t)m0 * DHEAD + (j * 64 + lane) * 8, Qs + j * 512);

    for (int it = 0; it < 13; ++it) {
        int kt = it * 64;
        // stage K tile (contiguous) and vT tile (rows d, cols kt..kt+63)
#pragma unroll
        for (int j = w; j < 8; j += 4)
            async_copy16(kbase + (size_t)kt * DHEAD + (j * 64 + lane) * 8, Ks + j * 512);
#pragma unroll
        for (int j = w; j < 8; j += 4) {
            int c = j * 64 + lane;
            int d = c >> 3, soff = (c & 7) * 8;
            async_copy16(vbase + (size_t)d * SP_LEN + kt + soff, Vts + j * 512);
        }
        __syncthreads();

        int nt = (kt + 64 <= S_LEN) ? 4 : 2;   // valid 16-col tiles

        // QK^T
        bf16x8 aq0 = *(const bf16x8*)(Qs + (w * 16 + lc) * 64 + kq);
        bf16x8 aq1 = *(const bf16x8*)(Qs + (w * 16 + lc) * 64 + 32 + kq);
        f32x4 sacc[4];
        for (int t = 0; t < nt; ++t) {
            bf16x8 bk0 = *(const bf16x8*)(Ks + (t * 16 + lc) * 64 + kq);
            bf16x8 bk1 = *(const bf16x8*)(Ks + (t * 16 + lc) * 64 + 32 + kq);
            f32x4 z = (f32x4){0.f, 0.f, 0.f, 0.f};
            z = __builtin_amdgcn_mfma_f32_16x16x32_bf16(aq0, bk0, z, 0, 0, 0);
            z = __builtin_amdgcn_mfma_f32_16x16x32_bf16(aq1, bk1, z, 0, 0, 0);
            sacc[t] = z;
        }

        // row max (across tiles, then across the 16 lanes of the quad)
        float rmax[4];
#pragma unroll
        for (int r = 0; r < 4; ++r) {
            float m = sacc[0][r];
            for (int t = 1; t < nt; ++t) m = fmaxf(m, sacc[t][r]);
            rmax[r] = m;
        }
#pragma unroll
        for (int off = 1; off < 16; off <<= 1)
#pragma unroll
            for (int r = 0; r < 4; ++r)
                rmax[r] = fmaxf(rmax[r], __shfl_xor(rmax[r], off));

        float alpha[4], rsum[4] = {0.f, 0.f, 0.f, 0.f};
#pragma unroll
        for (int r = 0; r < 4; ++r) {
            float mnew = fmaxf(mrow[r], rmax[r]);
            alpha[r] = exp2f(mrow[r] - mnew);
            mrow[r] = mnew;
        }
        // P = exp2(s - m), write bf16 to own wave's strip of Ps
        for (int t = 0; t < nt; ++t) {
#pragma unroll
            for (int r = 0; r < 4; ++r) {
                float p = exp2f(sacc[t][r] - mrow[r]);
                rsum[r] += p;
                Ps[(w * 16 + lq * 4 + r) * 72 + t * 16 + lc] = f2bf(p);
            }
        }
#pragma unroll
        for (int off = 1; off < 16; off <<= 1)
#pragma unroll
            for (int r = 0; r < 4; ++r)
                rsum[r] += __shfl_xor(rsum[r], off);
#pragma unroll
        for (int r = 0; r < 4; ++r) lrow[r] = lrow[r] * alpha[r] + rsum[r];

        // rescale O
#pragma unroll
        for (int t = 0; t < 4; ++t)
#pragma unroll
            for (int r = 0; r < 4; ++r) oacc[t][r] *= alpha[r];

        // PV: A = P strip (own wave), B = Vts[d][key]
        int nk = nt >> 1;
        for (int kstep = 0; kstep < nk; ++kstep) {
            bf16x8 ap = *(const bf16x8*)(Ps + (w * 16 + lc) * 72 + kstep * 32 + kq);
#pragma unroll
            for (int t = 0; t < 4; ++t) {
                bf16x8 bv = *(const bf16x8*)(Vts + (t * 16 + lc) * 64 + kstep * 32 + kq);
                oacc[t] = __builtin_amdgcn_mfma_f32_16x16x32_bf16(ap, bv, oacc[t], 0, 0, 0);
            }
        }
        __syncthreads();
    }

    // normalize + store (skip pad rows)
    float inv_l[4];
#pragma unroll
    for (int r = 0; r < 4; ++r) inv_l[r] = 1.0f / lrow[r];
#pragma unroll
    for (int t = 0; t < 4; ++t)
#pragma unroll
        for (int r = 0; r < 4; ++r) {
            int row = w * 16 + lq * 4 + r;
            int s = m0 + row;
            if (s < S_LEN) {
                int n = t * 16 + lc;
                o[((size_t)(b * S_LEN + s)) * C_DIM + h * DHEAD + n] = f2bf(oacc[t][r] * inv_l[r]);
            }
        }
}

// ---------------------------------------------------------------------------
// Host launcher
// ---------------------------------------------------------------------------
extern "C" void kernel_launch(void* const* d_in, const int* in_sizes, int n_in,
                              void* d_out, int out_size, void* d_ws, size_t ws_size,
                              hipStream_t stream) {
    const float* x      = (const float*)d_in[0];
    const float* conv_w = (const float*)d_in[1];
    const float* conv_b = (const float*)d_in[2];
    const float* ln1_g  = (const float*)d_in[3];
    const float* ln1_b  = (const float*)d_in[4];
    const float* qkv_w  = (const float*)d_in[5];
    const float* qkv_b  = (const float*)d_in[6];
    const float* proj_w = (const float*)d_in[7];
    const float* proj_b = (const float*)d_in[8];
    const float* ln2_g  = (const float*)d_in[9];
    const float* ln2_b  = (const float*)d_in[10];
    const float* fc1_w  = (const float*)d_in[11];
    const float* fc1_b  = (const float*)d_in[12];
    const float* fc2_w  = (const float*)d_in[13];
    const float* fc2_b  = (const float*)d_in[14];
    const float* lnf_g  = (const float*)d_in[15];
    const float* lnf_b  = (const float*)d_in[16];

    const size_t NTC = (size_t)NTOK * C_DIM;
    const size_t HSD = (size_t)BATCH * NHEAD * SP_LEN * DHEAD;  // 2,555,904
    float* ws = (float*)d_ws;
    float* h       = ws;                              // (B,S,C) f32
    float* qkv_out = h + NTC;                         // (B,S,3C) f32
    short* qb      = (short*)(qkv_out + (size_t)NTOK * 3 * C_DIM);
    short* kb      = qb + HSD;
    short* vtb     = kb + HSD;
    short* y_bf    = vtb + HSD;                       // (B,S,C) bf16
    short* big_bf  = y_bf + NTC;                      // (B,S,HID) bf16 / im2col
    short* wbuf    = big_bf + (size_t)NTOK * HID_DIM;
    short* embed_wt = wbuf + (size_t)HID_DIM * C_DIM;

    // ---- patch embed ----
    convert_bf_kernel<<<(768 * 768 + 255) / 256, 256, 0, stream>>>(conv_w, embed_wt, 768 * 768);
    im2col_kernel<<<(NTOK * 768 + 255) / 256, 256, 0, stream>>>(x, big_bf);
    gemm_mfma<64, false, false, false><<<dim3(C_DIM / 64, NTOK / 128), 256, 0, stream>>>(
        big_bf, embed_wt, conv_b, nullptr, h, NTOK, C_DIM, C_DIM);

    for (int l = 0; l < DEPTH_N; ++l) {
        const float* l1g = ln1_g + (size_t)l * C_DIM;
        const float* l1b = ln1_b + (size_t)l * C_DIM;
        const float* qw  = qkv_w + (size_t)l * C_DIM * 3 * C_DIM;
        const float* qbs = qkv_b + (size_t)l * 3 * C_DIM;
        const float* pw  = proj_w + (size_t)l * C_DIM * C_DIM;
        const float* pb  = proj_b + (size_t)l * C_DIM;
        const float* l2g = ln2_g + (size_t)l * C_DIM;
        const float* l2b = ln2_b + (size_t)l * C_DIM;
        const float* f1w = fc1_w + (size_t)l * C_DIM * HID_DIM;
        const float* f1b = fc1_b + (size_t)l * HID_DIM;
        const float* f2w = fc2_w + (size_t)l * HID_DIM * C_DIM;
        const float* f2b = fc2_b + (size_t)l * C_DIM;

        // qkv
        ln_kernel<true><<<NTOK, 256, 0, stream>>>(h, l1g, l1b, y_bf);
        transpose_convert_kernel<<<dim3(3 * C_DIM / 32, C_DIM / 32), 256, 0, stream>>>(
            qw, wbuf, C_DIM, 3 * C_DIM);
        gemm_mfma<128, false, false, false><<<dim3(3 * C_DIM / 128, NTOK / 128), 256, 0, stream>>>(
            y_bf, wbuf, qbs, nullptr, qkv_out, NTOK, 3 * C_DIM, C_DIM);

        // attention
        rope_qkv_kernel<<<dim3(13, BATCH * NHEAD), 256, 0, stream>>>(qkv_out, qb, kb, vtb);
        attn_mfma_kernel<<<dim3(13, BATCH * NHEAD), 256, 0, stream>>>(qb, kb, vtb, y_bf);

        // proj (+res into h)
        transpose_convert_kernel<<<dim3(C_DIM / 32, C_DIM / 32), 256, 0, stream>>>(
            pw, wbuf, C_DIM, C_DIM);
        gemm_mfma<64, false, true, false><<<dim3(C_DIM / 64, NTOK / 128), 256, 0, stream>>>(
            y_bf, wbuf, pb, h, h, NTOK, C_DIM, C_DIM);

        // mlp
        ln_kernel<true><<<NTOK, 256, 0, stream>>>(h, l2g, l2b, y_bf);
        transpose_convert_kernel<<<dim3(HID_DIM / 32, C_DIM / 32), 256, 0, stream>>>(
            f1w, wbuf, C_DIM, HID_DIM);
        gemm_mfma<128, true, false, true><<<dim3(HID_DIM / 128, NTOK / 128), 256, 0, stream>>>(
            y_bf, wbuf, f1b, nullptr, big_bf, NTOK, HID_DIM, C_DIM);
        transpose_convert_kernel<<<dim3(C_DIM / 32, HID_DIM / 32), 256, 0, stream>>>(
            f2w, wbuf, HID_DIM, C_DIM);
        gemm_mfma<64, false, true, false><<<dim3(C_DIM / 64, NTOK / 128), 256, 0, stream>>>(
            big_bf, wbuf, f2b, h, h, NTOK, C_DIM, HID_DIM);
    }

    ln_kernel<false><<<NTOK, 256, 0, stream>>>(h, lnf_g, lnf_b, d_out);
}

// Round 4
// 2799.242 us; speedup vs baseline: 4.4916x; 1.0682x over previous
//
#include <hip/hip_runtime.h>
#include <hip/hip_bf16.h>
#include <math.h>

#define S_LEN   800
#define SP_LEN  896              // padded to 7*128 for K/V
#define C_DIM   768
#define NHEAD   12
#define DHEAD   64
#define HID_DIM 3072
#define BATCH   4
#define NTOK    (BATCH * S_LEN)   // 3200
#define DEPTH_N 12

using bf16x8 = __attribute__((ext_vector_type(8))) short;
using f32x4  = __attribute__((ext_vector_type(4))) float;

__device__ inline short f2bf(float x) {
    unsigned u = __builtin_bit_cast(unsigned, x);
    u += 0x7fff + ((u >> 16) & 1);          // RNE
    return (short)(u >> 16);
}
__device__ inline float bf2f(short x) {
    unsigned u = ((unsigned)(unsigned short)x) << 16;
    return __builtin_bit_cast(float, u);
}

typedef const __attribute__((address_space(1))) void* gas_ptr;
typedef __attribute__((address_space(3))) void* las_ptr;
__device__ inline void async_copy16(const void* g, void* l) {
    __builtin_amdgcn_global_load_lds((gas_ptr)g, (las_ptr)l, 16, 0, 0);
}

// ---------------------------------------------------------------------------
// Transpose + convert: W fp32 [K][N] -> Wt bf16 [N][K]
// ---------------------------------------------------------------------------
__global__ __launch_bounds__(256)
void transpose_convert_kernel(const float* __restrict__ W, short* __restrict__ Wt,
                              int K, int N) {
    __shared__ float tile[32][33];
    int k0 = blockIdx.y * 32, n0 = blockIdx.x * 32;
    int tx = threadIdx.x & 31, ty = threadIdx.x >> 5;   // 32 x 8
#pragma unroll
    for (int i = ty; i < 32; i += 8)
        tile[i][tx] = W[(size_t)(k0 + i) * N + n0 + tx];
    __syncthreads();
#pragma unroll
    for (int i = ty; i < 32; i += 8)
        Wt[(size_t)(n0 + i) * K + k0 + tx] = f2bf(tile[tx][i]);
}

__global__ void convert_bf_kernel(const float* __restrict__ a, short* __restrict__ o, int n) {
    int i = blockIdx.x * 256 + threadIdx.x;
    if (i < n) o[i] = f2bf(a[i]);
}

// ---------------------------------------------------------------------------
// im2col (bf16 out) for the dual patch embed.
// ---------------------------------------------------------------------------
__global__ void im2col_kernel(const float* __restrict__ x, short* __restrict__ A) {
    int idx = blockIdx.x * 256 + threadIdx.x;          // 3200*768
    if (idx >= NTOK * 768) return;
    int kk = idx % 768;
    int s  = (idx / 768) % S_LEN;
    int b  = idx / (768 * S_LEN);
    int c  = kk / 256;
    int i  = (kk / 16) % 16;
    int j  = kk % 16;
    int half = s / 400, ss = s % 400;
    int hg = ss / 20, wg = ss % 20;
    int ch = half * 3 + c;
    A[idx] = f2bf(x[((size_t)(b * 6 + ch) * 320 + hg * 16 + i) * 320 + wg * 16 + j]);
}

// ---------------------------------------------------------------------------
// bf16 MFMA GEMM: C = A[M,K] @ Bt[N,K]^T + bias (+res)(+GELU).
// BM=128, BK=64, 256 thr. XOR-swizzled LDS (chunk ^ row&7): conflict-free
// fragment reads while keeping global_load_lds staging.
// ---------------------------------------------------------------------------
template <int BN, bool GELU, bool RES, bool OBF>
__global__ __launch_bounds__(256)
void gemm_mfma(const short* __restrict__ A, const short* __restrict__ Bt,
               const float* __restrict__ bias, const float* __restrict__ res,
               void* __restrict__ Cout, int M, int N, int K) {
    constexpr int BM = 128, BK = 64;
    constexpr int TI = (BN == 128) ? 4 : 2;
    constexpr int TJ = 4;
    constexpr int ACALLS = BM * BK / (8 * 64);   // 16
    constexpr int BCALLS = BN * BK / (8 * 64);   // 16 or 8

    __shared__ __align__(16) short As[BM * BK];  // [row][k-chunk swizzled]
    __shared__ __align__(16) short Bs[BN * BK];

    int tid = threadIdx.x;
    int w = tid >> 6, lane = tid & 63;
    int m0 = blockIdx.y * BM, n0 = blockIdx.x * BN;

    int wr = (BN == 128) ? (w >> 1) * 64 : w * 32;
    int wc = (BN == 128) ? (w & 1) * 64 : 0;

    f32x4 acc[TI][TJ];
#pragma unroll
    for (int i = 0; i < TI; ++i)
#pragma unroll
        for (int j = 0; j < TJ; ++j)
            acc[i][j] = (f32x4){0.f, 0.f, 0.f, 0.f};

    int lc = lane & 15, lq = lane >> 4;

    for (int k0 = 0; k0 < K; k0 += BK) {
#pragma unroll
        for (int j = w; j < ACALLS; j += 4) {
            int c = j * 64 + lane;
            int row = c >> 3, p = c & 7, q = p ^ (row & 7);
            async_copy16(A + (size_t)(m0 + row) * K + k0 + q * 8, As + j * 512);
        }
#pragma unroll
        for (int j = w; j < BCALLS; j += 4) {
            int c = j * 64 + lane;
            int row = c >> 3, p = c & 7, q = p ^ (row & 7);
            async_copy16(Bt + (size_t)(n0 + row) * K + k0 + q * 8, Bs + j * 512);
        }
        __syncthreads();

#pragma unroll
        for (int h = 0; h < 2; ++h) {
            bf16x8 afrag[TI], bfrag[TJ];
#pragma unroll
            for (int i = 0; i < TI; ++i) {
                int row = wr + i * 16 + lc;
                afrag[i] = *(const bf16x8*)(As + row * 64 + ((((h << 2) | lq)) ^ (row & 7)) * 8);
            }
#pragma unroll
            for (int j = 0; j < TJ; ++j) {
                int col = wc + j * 16 + lc;
                bfrag[j] = *(const bf16x8*)(Bs + col * 64 + ((((h << 2) | lq)) ^ (col & 7)) * 8);
            }
#pragma unroll
            for (int i = 0; i < TI; ++i)
#pragma unroll
                for (int j = 0; j < TJ; ++j)
                    acc[i][j] = __builtin_amdgcn_mfma_f32_16x16x32_bf16(
                        afrag[i], bfrag[j], acc[i][j], 0, 0, 0);
        }
        __syncthreads();
    }

    int rbase = lq * 4;
#pragma unroll
    for (int i = 0; i < TI; ++i)
#pragma unroll
        for (int j = 0; j < TJ; ++j)
#pragma unroll
            for (int r = 0; r < 4; ++r) {
                int m = m0 + wr + i * 16 + rbase + r;
                int n = n0 + wc + j * 16 + lc;
                float v = acc[i][j][r] + bias[n];
                if (RES) v += res[(size_t)m * N + n];
                if (GELU) v = 0.5f * v * (1.0f + erff(v * 0.70710678118654752f));
                if (OBF) ((short*)Cout)[(size_t)m * N + n] = f2bf(v);
                else     ((float*)Cout)[(size_t)m * N + n] = v;
            }
}

// ---------------------------------------------------------------------------
// LayerNorm (unchanged)
// ---------------------------------------------------------------------------
template <bool OBF>
__global__ __launch_bounds__(256)
void ln_kernel(const float* __restrict__ x, const float* __restrict__ g,
               const float* __restrict__ bta, void* __restrict__ yv) {
    int row = blockIdx.x;
    const float* xr = x + (size_t)row * C_DIM;
    int tid = threadIdx.x;

    float v0 = xr[tid], v1 = xr[tid + 256], v2 = xr[tid + 512];
    float s  = v0 + v1 + v2;
    float sq = v0 * v0 + v1 * v1 + v2 * v2;
#pragma unroll
    for (int off = 32; off; off >>= 1) {
        s  += __shfl_down(s, off);
        sq += __shfl_down(sq, off);
    }
    __shared__ float red1[4], red2[4];
    __shared__ float mean_s, rstd_s;
    int wv = tid / 64, lane = tid % 64;
    if (lane == 0) { red1[wv] = s; red2[wv] = sq; }
    __syncthreads();
    if (tid == 0) {
        float S1 = red1[0] + red1[1] + red1[2] + red1[3];
        float S2 = red2[0] + red2[1] + red2[2] + red2[3];
        float m = S1 / (float)C_DIM;
        float var = S2 / (float)C_DIM - m * m;
        mean_s = m;
        rstd_s = rsqrtf(var + 1e-6f);
    }
    __syncthreads();
    float m = mean_s, r = rstd_s;
    float o0 = (v0 - m) * r * g[tid]       + bta[tid];
    float o1 = (v1 - m) * r * g[tid + 256] + bta[tid + 256];
    float o2 = (v2 - m) * r * g[tid + 512] + bta[tid + 512];
    if (OBF) {
        short* yr = (short*)yv + (size_t)row * C_DIM;
        yr[tid] = f2bf(o0); yr[tid + 256] = f2bf(o1); yr[tid + 512] = f2bf(o2);
    } else {
        float* yr = (float*)yv + (size_t)row * C_DIM;
        yr[tid] = o0; yr[tid + 256] = o1; yr[tid + 512] = o2;
    }
}

// ---------------------------------------------------------------------------
// RoPE + split from bf16 qkv (tok, 2304) ->
//   qb/kb: (bh, s[896], dh) bf16 (q pre-scaled by 0.125*log2e), vtb: (bh, dh, s[896])
// grid (14, 48), 256 thr. Pad rows zeroed.
// ---------------------------------------------------------------------------
__global__ __launch_bounds__(256)
void rope_qkv_kernel(const short* __restrict__ qkv, short* __restrict__ qb,
                     short* __restrict__ kb, short* __restrict__ vtb) {
    int st = blockIdx.x;           // 0..13
    int bh = blockIdx.y;           // 0..47
    int b = bh / NHEAD, h = bh % NHEAD;
    int s0 = st * 64;

    __shared__ __align__(16) short vlds[64][72];

    int tid = threadIdx.x;
    int sl = tid >> 2;             // s row within tile
    int dc = (tid & 3) * 16;       // d chunk base
    int s = s0 + sl;

    short qo[16], ko[16];
    if (s < S_LEN) {
        const short* base = qkv + ((size_t)(b * S_LEN + s)) * (3 * C_DIM) + h * DHEAD + dc;
        short qsh[16], ksh[16], vsh[16];
        *(bf16x8*)(qsh)     = *(const bf16x8*)(base);
        *(bf16x8*)(qsh + 8) = *(const bf16x8*)(base + 8);
        *(bf16x8*)(ksh)     = *(const bf16x8*)(base + C_DIM);
        *(bf16x8*)(ksh + 8) = *(const bf16x8*)(base + C_DIM + 8);
        *(bf16x8*)(vsh)     = *(const bf16x8*)(base + 2 * C_DIM);
        *(bf16x8*)(vsh + 8) = *(const bf16x8*)(base + 2 * C_DIM + 8);
        float qv[16], kv[16];
#pragma unroll
        for (int i = 0; i < 16; ++i) { qv[i] = bf2f(qsh[i]); kv[i] = bf2f(ksh[i]); }
#pragma unroll
        for (int i = 0; i < 16; ++i) {
            int d = dc + i;
            float ang = (float)s * exp2f(-(float)(d & 31) * 0.41524101186092029f); // log2(1e4)/16
            float c = cosf(ang), sn = sinf(ang);
            float sign = (i & 1) ? 1.0f : -1.0f;
            qo[i] = f2bf((qv[i] * c + sign * qv[i ^ 1] * sn) * 0.18033688011112042f);
            ko[i] = f2bf(kv[i] * c + sign * kv[i ^ 1] * sn);
        }
        *(bf16x8*)&vlds[sl][dc]     = *(bf16x8*)(vsh);
        *(bf16x8*)&vlds[sl][dc + 8] = *(bf16x8*)(vsh + 8);
    } else {
#pragma unroll
        for (int i = 0; i < 16; ++i) { qo[i] = 0; ko[i] = 0; vlds[sl][dc + i] = 0; }
    }
    {
        short* qd = qb + ((size_t)bh * SP_LEN + s) * DHEAD + dc;
        short* kd = kb + ((size_t)bh * SP_LEN + s) * DHEAD + dc;
        *(bf16x8*)(qd)     = *(bf16x8*)(qo);
        *(bf16x8*)(qd + 8) = *(bf16x8*)(qo + 8);
        *(bf16x8*)(kd)     = *(bf16x8*)(ko);
        *(bf16x8*)(kd + 8) = *(bf16x8*)(ko + 8);
    }
    __syncthreads();
    {
        int dr = tid >> 2, sc = (tid & 3) * 16;
        short vo[16];
#pragma unroll
        for (int i = 0; i < 16; ++i) vo[i] = vlds[sc + i][dr];
        short* vd = vtb + ((size_t)bh * DHEAD + dr) * SP_LEN + s0 + sc;
        *(bf16x8*)(vd)     = *(bf16x8*)(vo);
        *(bf16x8*)(vd + 8) = *(bf16x8*)(vo + 8);
    }
}

// ---------------------------------------------------------------------------
// Flash attention, bf16 MFMA, K-tile=128, XOR-swizzled LDS.
// Block = 64 q-rows of one (b,h); 4 waves each own a 16-row strip.
// 7 key-tiles of 128 (last: 32 valid). Softmax base-2 (q pre-scaled).
// ---------------------------------------------------------------------------
__global__ __launch_bounds__(256)
void attn_mfma_kernel(const short* __restrict__ qb, const short* __restrict__ kb,
                      const short* __restrict__ vtb, short* __restrict__ o) {
    int qt = blockIdx.x;           // 0..12
    int bh = blockIdx.y;           // 0..47
    int b = bh / NHEAD, h = bh % NHEAD;
    int m0 = qt * 64;

    __shared__ __align__(16) short Qs[64 * 64];
    __shared__ __align__(16) short Ks[128 * 64];
    __shared__ __align__(16) short Vts[64 * 128];
    __shared__ __align__(16) short Ps[64 * 136];

    int tid = threadIdx.x;
    int w = tid >> 6, lane = tid & 63;
    int lc = lane & 15, lq = lane >> 4;
    int kq = lq * 8;

    const short* qbase = qb + (size_t)bh * SP_LEN * DHEAD;
    const short* kbase = kb + (size_t)bh * SP_LEN * DHEAD;
    const short* vbase = vtb + (size_t)bh * DHEAD * SP_LEN;

    f32x4 oacc[4];
#pragma unroll
    for (int t = 0; t < 4; ++t) oacc[t] = (f32x4){0.f, 0.f, 0.f, 0.f};
    float mrow[4] = {-3.0e38f, -3.0e38f, -3.0e38f, -3.0e38f};
    float lrow[4] = {0.f, 0.f, 0.f, 0.f};

    // stage Q once (swizzled)
#pragma unroll
    for (int j = w; j < 8; j += 4) {
        int c = j * 64 + lane;
        int row = c >> 3, p = c & 7, q = p ^ (row & 7);
        async_copy16(qbase + (size_t)(m0 + row) * DHEAD + q * 8, Qs + j * 512);
    }

    for (int it = 0; it < 7; ++it) {
        int kt = it * 128;
#pragma unroll
        for (int j = w; j < 16; j += 4) {
            int c = j * 64 + lane;
            int row = c >> 3, p = c & 7, q = p ^ (row & 7);
            async_copy16(kbase + (size_t)(kt + row) * DHEAD + q * 8, Ks + j * 512);
        }
#pragma unroll
        for (int j = w; j < 16; j += 4) {
            int c = j * 64 + lane;
            int d = c >> 4, p = c & 15, sq = p ^ (d & 15);
            async_copy16(vbase + (size_t)d * SP_LEN + kt + sq * 8, Vts + j * 512);
        }
        __syncthreads();

        int nt = (it < 6) ? 8 : 2;     // valid 16-col tiles

        int qrow = w * 16 + lc;
        bf16x8 aq0 = *(const bf16x8*)(Qs + qrow * 64 + ((lq) ^ (qrow & 7)) * 8);
        bf16x8 aq1 = *(const bf16x8*)(Qs + qrow * 64 + ((4 | lq) ^ (qrow & 7)) * 8);

        f32x4 sacc[8];
        for (int t = 0; t < nt; ++t) {
            int kr = t * 16 + lc;
            bf16x8 bk0 = *(const bf16x8*)(Ks + kr * 64 + ((lq) ^ (kr & 7)) * 8);
            bf16x8 bk1 = *(const bf16x8*)(Ks + kr * 64 + ((4 | lq) ^ (kr & 7)) * 8);
            f32x4 z = (f32x4){0.f, 0.f, 0.f, 0.f};
            z = __builtin_amdgcn_mfma_f32_16x16x32_bf16(aq0, bk0, z, 0, 0, 0);
            z = __builtin_amdgcn_mfma_f32_16x16x32_bf16(aq1, bk1, z, 0, 0, 0);
            sacc[t] = z;
        }

        float rmax[4];
#pragma unroll
        for (int r = 0; r < 4; ++r) {
            float m = sacc[0][r];
            for (int t = 1; t < nt; ++t) m = fmaxf(m, sacc[t][r]);
            rmax[r] = m;
        }
#pragma unroll
        for (int off = 1; off < 16; off <<= 1)
#pragma unroll
            for (int r = 0; r < 4; ++r)
                rmax[r] = fmaxf(rmax[r], __shfl_xor(rmax[r], off));

        float alpha[4], rsum[4] = {0.f, 0.f, 0.f, 0.f};
#pragma unroll
        for (int r = 0; r < 4; ++r) {
            float mnew = fmaxf(mrow[r], rmax[r]);
            alpha[r] = exp2f(mrow[r] - mnew);
            mrow[r] = mnew;
        }
        for (int t = 0; t < nt; ++t) {
#pragma unroll
            for (int r = 0; r < 4; ++r) {
                float p = exp2f(sacc[t][r] - mrow[r]);
                rsum[r] += p;
                Ps[(w * 16 + lq * 4 + r) * 136 + t * 16 + lc] = f2bf(p);
            }
        }
#pragma unroll
        for (int off = 1; off < 16; off <<= 1)
#pragma unroll
            for (int r = 0; r < 4; ++r)
                rsum[r] += __shfl_xor(rsum[r], off);
#pragma unroll
        for (int r = 0; r < 4; ++r) lrow[r] = lrow[r] * alpha[r] + rsum[r];
#pragma unroll
        for (int t = 0; t < 4; ++t)
#pragma unroll
            for (int r = 0; r < 4; ++r) oacc[t][r] *= alpha[r];

        int nk = (nt == 8) ? 4 : 1;
        for (int kstep = 0; kstep < nk; ++kstep) {
            bf16x8 ap = *(const bf16x8*)(Ps + (w * 16 + lc) * 136 + kstep * 32 + kq);
#pragma unroll
            for (int t = 0; t < 4; ++t) {
                int dr = t * 16 + lc;
                bf16x8 bv = *(const bf16x8*)(Vts + dr * 128 + ((((kstep << 2) | lq)) ^ (dr & 15)) * 8);
                oacc[t] = __builtin_amdgcn_mfma_f32_16x16x32_bf16(ap, bv, oacc[t], 0, 0, 0);
            }
        }
        __syncthreads();
    }

    float inv_l[4];
#pragma unroll
    for (int r = 0; r < 4; ++r) inv_l[r] = 1.0f / lrow[r];
#pragma unroll
    for (int t = 0; t < 4; ++t)
#pragma unroll
        for (int r = 0; r < 4; ++r) {
            int row = w * 16 + lq * 4 + r;
            int s = m0 + row;
            if (s < S_LEN) {
                int n = t * 16 + lc;
                o[((size_t)(b * S_LEN + s)) * C_DIM + h * DHEAD + n] = f2bf(oacc[t][r] * inv_l[r]);
            }
        }
}

// ---------------------------------------------------------------------------
// Host launcher
// ---------------------------------------------------------------------------
extern "C" void kernel_launch(void* const* d_in, const int* in_sizes, int n_in,
                              void* d_out, int out_size, void* d_ws, size_t ws_size,
                              hipStream_t stream) {
    const float* x      = (const float*)d_in[0];
    const float* conv_w = (const float*)d_in[1];
    const float* conv_b = (const float*)d_in[2];
    const float* ln1_g  = (const float*)d_in[3];
    const float* ln1_b  = (const float*)d_in[4];
    const float* qkv_w  = (const float*)d_in[5];
    const float* qkv_b  = (const float*)d_in[6];
    const float* proj_w = (const float*)d_in[7];
    const float* proj_b = (const float*)d_in[8];
    const float* ln2_g  = (const float*)d_in[9];
    const float* ln2_b  = (const float*)d_in[10];
    const float* fc1_w  = (const float*)d_in[11];
    const float* fc1_b  = (const float*)d_in[12];
    const float* fc2_w  = (const float*)d_in[13];
    const float* fc2_b  = (const float*)d_in[14];
    const float* lnf_g  = (const float*)d_in[15];
    const float* lnf_b  = (const float*)d_in[16];

    const size_t NTC = (size_t)NTOK * C_DIM;
    const size_t HSD = (size_t)BATCH * NHEAD * SP_LEN * DHEAD;  // 2,752,512
    float* ws = (float*)d_ws;
    float* h       = ws;                              // (B,S,C) f32
    short* qkv_bf  = (short*)(h + NTC);               // (B,S,3C) bf16
    short* qb      = qkv_bf + (size_t)NTOK * 3 * C_DIM;
    short* kb      = qb + HSD;
    short* vtb     = kb + HSD;
    short* y_bf    = vtb + HSD;                       // (B,S,C) bf16
    short* big_bf  = y_bf + NTC;                      // (B,S,HID) bf16 / im2col
    short* wbuf    = big_bf + (size_t)NTOK * HID_DIM;
    short* embed_wt = wbuf + (size_t)HID_DIM * C_DIM;

    // ---- patch embed ----
    convert_bf_kernel<<<(768 * 768 + 255) / 256, 256, 0, stream>>>(conv_w, embed_wt, 768 * 768);
    im2col_kernel<<<(NTOK * 768 + 255) / 256, 256, 0, stream>>>(x, big_bf);
    gemm_mfma<64, false, false, false><<<dim3(C_DIM / 64, NTOK / 128), 256, 0, stream>>>(
        big_bf, embed_wt, conv_b, nullptr, h, NTOK, C_DIM, C_DIM);

    for (int l = 0; l < DEPTH_N; ++l) {
        const float* l1g = ln1_g + (size_t)l * C_DIM;
        const float* l1b = ln1_b + (size_t)l * C_DIM;
        const float* qw  = qkv_w + (size_t)l * C_DIM * 3 * C_DIM;
        const float* qbs = qkv_b + (size_t)l * 3 * C_DIM;
        const float* pw  = proj_w + (size_t)l * C_DIM * C_DIM;
        const float* pb  = proj_b + (size_t)l * C_DIM;
        const float* l2g = ln2_g + (size_t)l * C_DIM;
        const float* l2b = ln2_b + (size_t)l * C_DIM;
        const float* f1w = fc1_w + (size_t)l * C_DIM * HID_DIM;
        const float* f1b = fc1_b + (size_t)l * HID_DIM;
        const float* f2w = fc2_w + (size_t)l * HID_DIM * C_DIM;
        const float* f2b = fc2_b + (size_t)l * C_DIM;

        // qkv (bf16 out)
        ln_kernel<true><<<NTOK, 256, 0, stream>>>(h, l1g, l1b, y_bf);
        transpose_convert_kernel<<<dim3(3 * C_DIM / 32, C_DIM / 32), 256, 0, stream>>>(
            qw, wbuf, C_DIM, 3 * C_DIM);
        gemm_mfma<128, false, false, true><<<dim3(3 * C_DIM / 128, NTOK / 128), 256, 0, stream>>>(
            y_bf, wbuf, qbs, nullptr, qkv_bf, NTOK, 3 * C_DIM, C_DIM);

        // attention
        rope_qkv_kernel<<<dim3(14, BATCH * NHEAD), 256, 0, stream>>>(qkv_bf, qb, kb, vtb);
        attn_mfma_kernel<<<dim3(13, BATCH * NHEAD), 256, 0, stream>>>(qb, kb, vtb, y_bf);

        // proj (+res into h)
        transpose_convert_kernel<<<dim3(C_DIM / 32, C_DIM / 32), 256, 0, stream>>>(
            pw, wbuf, C_DIM, C_DIM);
        gemm_mfma<64, false, true, false><<<dim3(C_DIM / 64, NTOK / 128), 256, 0, stream>>>(
            y_bf, wbuf, pb, h, h, NTOK, C_DIM, C_DIM);

        // mlp
        ln_kernel<true><<<NTOK, 256, 0, stream>>>(h, l2g, l2b, y_bf);
        transpose_convert_kernel<<<dim3(HID_DIM / 32, C_DIM / 32), 256, 0, stream>>>(
            f1w, wbuf, C_DIM, HID_DIM);
        gemm_mfma<128, true, false, true><<<dim3(HID_DIM / 128, NTOK / 128), 256, 0, stream>>>(
            y_bf, wbuf, f1b, nullptr, big_bf, NTOK, HID_DIM, C_DIM);
        transpose_convert_kernel<<<dim3(C_DIM / 32, HID_DIM / 32), 256, 0, stream>>>(
            f2w, wbuf, HID_DIM, C_DIM);
        gemm_mfma<64, false, true, false><<<dim3(C_DIM / 64, NTOK / 128), 256, 0, stream>>>(
            big_bf, wbuf, f2b, h, h, NTOK, C_DIM, HID_DIM);
    }

    ln_kernel<false><<<NTOK, 256, 0, stream>>>(h, lnf_g, lnf_b, d_out);
}